// Round 9
// baseline (245.801 us; speedup 1.0000x reference)
//
#include <hip/hip_runtime.h>
#include <math.h>

// Problem constants
#define DIM   256
#define NST   256
#define LSEQ  512
#define BAT   2
#define DTSZ  64
#define PCOLS 576
#define NROWS 1024

constexpr float LOG2E = 1.4426950408889634f;

__device__ __forceinline__ float fexp2(float v) {
#if __has_builtin(__builtin_amdgcn_exp2f)
    return __builtin_amdgcn_exp2f(v);
#else
    return exp2f(v);
#endif
}

__device__ __forceinline__ float softplusf(float v) {
    return (v > 20.f) ? v : log1pf(__expf(v));
}

// ---------------- proj: x@W_in (+ dt GEMM + softplus + dt*x). 512 blocks x 256.
// (unchanged from round 6/7/8)
__global__ __launch_bounds__(256) void proj_kernel(
    const float* __restrict__ x, const float* __restrict__ W_in,
    const float* __restrict__ W_dt, const float* __restrict__ b_dt,
    float* __restrict__ bet, float* __restrict__ gam,
    float* __restrict__ dtp, float* __restrict__ dtxp)
{
    __shared__ float xs[2][DIM];
    __shared__ float draw[2][DTSZ];
    const int j = threadIdx.x;
    const int row0 = blockIdx.x * 2;

    #pragma unroll
    for (int r = 0; r < 2; ++r) xs[r][j] = x[(row0 + r) * DIM + j];
    __syncthreads();

    float acc0[2] = {0.f, 0.f}, acc1[2] = {0.f, 0.f}, acc2[2] = {0.f, 0.f};
    const bool has2 = (j < 64);

    for (int kk = 0; kk < DIM; kk += 16) {
        float w0[16], w1[16], w2[16];
        #pragma unroll
        for (int u = 0; u < 16; ++u) {
            const int k = kk + u;
            w0[u] = W_in[k * PCOLS + j];
            w1[u] = W_in[k * PCOLS + 256 + j];
            w2[u] = has2 ? W_in[k * PCOLS + 512 + j] : 0.f;
        }
        #pragma unroll
        for (int r = 0; r < 2; ++r) {
            #pragma unroll
            for (int q = 0; q < 4; ++q) {
                float4 xv = *(const float4*)&xs[r][kk + q * 4];
                const float xa[4] = {xv.x, xv.y, xv.z, xv.w};
                #pragma unroll
                for (int u = 0; u < 4; ++u) {
                    const int uu = q * 4 + u;
                    acc0[r] = fmaf(xa[u], w0[uu], acc0[r]);
                    acc1[r] = fmaf(xa[u], w1[uu], acc1[r]);
                    acc2[r] = fmaf(xa[u], w2[uu], acc2[r]);
                }
            }
        }
    }

    #pragma unroll
    for (int r = 0; r < 2; ++r) {
        const int row = row0 + r;
        if (has2) {
            draw[r][j] = acc0[r];
            bet[row * NST + 192 + j] = acc1[r];
            gam[row * NST + 192 + j] = acc2[r];
        } else {
            bet[row * NST + (j - 64)] = acc0[r];
            gam[row * NST + (j - 64)] = acc1[r];
        }
    }
    __syncthreads();

    float bd = b_dt[j];
    float accd[2] = {bd, bd};
    #pragma unroll 16
    for (int k = 0; k < DTSZ; ++k) {
        float w = W_dt[k * DIM + j];
        #pragma unroll
        for (int r = 0; r < 2; ++r) accd[r] = fmaf(draw[r][k], w, accd[r]);
    }
    #pragma unroll
    for (int r = 0; r < 2; ++r) {
        const int row = row0 + r;
        float sp = softplusf(accd[r]);
        dtp[row * DIM + j]  = sp;
        dtxp[row * DIM + j] = sp * xs[r][j];
    }
}

// ---------------- scan1w: single-pass scan, BARRIER-FREE main loop.
// 512 blocks (one per (b,d)) x 256 threads. Wave w owns n in [64w, 64w+64).
// Per 8-step window: wave-private LDS transpose (part[w][8][65], lgkmcnt-only,
// no __syncthreads) + 3 shfl_xor; per-wave step-sums parked in ypart[w][512].
// Cross-wave combine happens ONCE after the loop -> vmcnt prefetch queue for
// beta/gamma is never drained by a barrier (the R8 diagnosis: 32 barriers x
// s_waitcnt vmcnt(0) killed the pipeline).
__global__ __launch_bounds__(256) void scan1w(
    const float* __restrict__ x,          // [NROWS, DIM]
    const float* __restrict__ alpha_log,  // [DIM, NST]
    const float* __restrict__ delta,      // [DIM]
    const float* __restrict__ bet,        // [NROWS, NST]
    const float* __restrict__ gam,        // [NROWS, NST]
    const float* __restrict__ dtp,        // [NROWS, DIM]
    const float* __restrict__ dtxp,       // [NROWS, DIM]
    float* __restrict__ out)              // [NROWS, DIM]
{
    __shared__ float dts[LSEQ], dxs[LSEQ];       // 2 KB + 2 KB
    __shared__ float part[4][8 * 65];            // 8.3 KB wave-private scratch
    __shared__ float ypart[4][LSEQ];             // 8 KB per-wave step sums
    const int tid = threadIdx.x;
    const int wv  = tid >> 6;                    // wave 0..3
    const int ln  = tid & 63;                    // lane in wave
    const int n   = tid;                         // state index (wave wv: n=64wv+ln)
    const int d = blockIdx.x & 255;
    const int b = blockIdx.x >> 8;
    const int rb = b * LSEQ;

    // Stage dt/dtx columns for all 512 steps (one-time).
    #pragma unroll
    for (int it = 0; it < 2; ++it) {
        const int l = tid + it * 256;
        dts[l] = dtp [(rb + l) * DIM + d];
        dxs[l] = dtxp[(rb + l) * DIM + d];
    }
    const float aln = -__expf(alpha_log[d * NST + n]) * LOG2E;
    const float dv  = delta[d];
    __syncthreads();                             // barrier #1 (staging)

    float s = 0.f;
    float be[4][8], ga[4][8];                    // 4-buffer rotation, 2 windows ahead
    #pragma unroll
    for (int pw = 0; pw < 2; ++pw) {
        #pragma unroll
        for (int t = 0; t < 8; ++t) {
            be[pw][t] = bet[(rb + pw * 8 + t) * NST + n];
            ga[pw][t] = gam[(rb + pw * 8 + t) * NST + n];
        }
    }

    const int th  = ln >> 3;                     // reducer: step index within window
    const int seg = ln & 7;                      // reducer: n-segment

    for (int w8 = 0; w8 < 64; ++w8) {
        const int cur = w8 & 3;
        const int pf  = (w8 + 2) & 3;
        if (w8 + 2 < 64) {                       // keep 2 windows in flight
            #pragma unroll
            for (int t = 0; t < 8; ++t) {
                be[pf][t] = bet[(rb + (w8 + 2) * 8 + t) * NST + n];
                ga[pf][t] = gam[(rb + (w8 + 2) * 8 + t) * NST + n];
            }
        }
        // dt/dtx for this window: broadcast b128 LDS reads
        float4 dta = *(const float4*)&dts[w8 * 8];
        float4 dtb = *(const float4*)&dts[w8 * 8 + 4];
        float4 dxa = *(const float4*)&dxs[w8 * 8];
        float4 dxb = *(const float4*)&dxs[w8 * 8 + 4];
        const float dtw[8] = {dta.x, dta.y, dta.z, dta.w, dtb.x, dtb.y, dtb.z, dtb.w};
        const float dxw[8] = {dxa.x, dxa.y, dxa.z, dxa.w, dxb.x, dxb.y, dxb.z, dxb.w};

        float sy[8];
        #pragma unroll
        for (int t = 0; t < 8; ++t) {
            float a = fexp2(dtw[t] * aln);
            s = fmaf(a, s, dxw[t] * be[cur][t]);
            sy[t] = s * ga[cur][t];
        }
        // wave-private transpose: write rows (free: consecutive lanes), then
        // rotated column reads (~2-3-way worst case, 1/step amortized)
        #pragma unroll
        for (int t = 0; t < 8; ++t) part[wv][t * 65 + ln] = sy[t];

        float sum = 0.f;
        #pragma unroll
        for (int k = 0; k < 8; ++k)
            sum += part[wv][th * 65 + seg * 8 + ((k + ln) & 7)];
        sum += __shfl_xor(sum, 1);
        sum += __shfl_xor(sum, 2);
        sum += __shfl_xor(sum, 4);
        if (seg == 0) ypart[wv][w8 * 8 + th] = sum;   // lanes 0,8,..,56: steps 0..7
    }

    __syncthreads();                             // barrier #2 (final combine)
    #pragma unroll
    for (int it = 0; it < 2; ++it) {
        const int l = tid + it * 256;
        float y = ypart[0][l] + ypart[1][l] + ypart[2][l] + ypart[3][l];
        const int oidx = (rb + l) * DIM + d;
        out[oidx] = y + x[oidx] * dv;
    }
}

extern "C" void kernel_launch(void* const* d_in, const int* in_sizes, int n_in,
                              void* d_out, int out_size, void* d_ws, size_t ws_size,
                              hipStream_t stream) {
    const float* x         = (const float*)d_in[0];
    const float* W_in      = (const float*)d_in[1];
    const float* W_dt      = (const float*)d_in[2];
    const float* b_dt      = (const float*)d_in[3];
    const float* alpha_log = (const float*)d_in[4];
    const float* delta     = (const float*)d_in[5];
    float* out = (float*)d_out;

    // Workspace: bet/gam/dtp/dtxp = 4 MB total
    float* bet  = (float*)d_ws;
    float* gam  = bet  + NROWS * NST;
    float* dtp  = gam  + NROWS * NST;
    float* dtxp = dtp  + NROWS * DIM;

    proj_kernel<<<NROWS / 2, 256, 0, stream>>>(x, W_in, W_dt, b_dt, bet, gam, dtp, dtxp);
    scan1w<<<BAT * DIM, 256, 0, stream>>>(x, alpha_log, delta, bet, gam, dtp, dtxp, out);
}

// Round 10
// 124.926 us; speedup vs baseline: 1.9676x; 1.9676x over previous
//
#include <hip/hip_runtime.h>
#include <math.h>

// Problem constants
#define DIM   256
#define NST   256
#define LSEQ  512
#define BAT   2
#define DTSZ  64
#define PCOLS 576
#define NROWS 1024

constexpr float LOG2E = 1.4426950408889634f;

__device__ __forceinline__ float fexp2(float v) {
#if __has_builtin(__builtin_amdgcn_exp2f)
    return __builtin_amdgcn_exp2f(v);
#else
    return exp2f(v);
#endif
}

__device__ __forceinline__ float softplusf(float v) {
    return (v > 20.f) ? v : log1pf(__expf(v));
}

// ---------------- proj: x@W_in (+ dt GEMM + softplus + dt*x). 512 blocks x 256.
// (unchanged — verified since round 6)
__global__ __launch_bounds__(256) void proj_kernel(
    const float* __restrict__ x, const float* __restrict__ W_in,
    const float* __restrict__ W_dt, const float* __restrict__ b_dt,
    float* __restrict__ bet, float* __restrict__ gam,
    float* __restrict__ dtp, float* __restrict__ dtxp)
{
    __shared__ float xs[2][DIM];
    __shared__ float draw[2][DTSZ];
    const int j = threadIdx.x;
    const int row0 = blockIdx.x * 2;

    #pragma unroll
    for (int r = 0; r < 2; ++r) xs[r][j] = x[(row0 + r) * DIM + j];
    __syncthreads();

    float acc0[2] = {0.f, 0.f}, acc1[2] = {0.f, 0.f}, acc2[2] = {0.f, 0.f};
    const bool has2 = (j < 64);

    for (int kk = 0; kk < DIM; kk += 16) {
        float w0[16], w1[16], w2[16];
        #pragma unroll
        for (int u = 0; u < 16; ++u) {
            const int k = kk + u;
            w0[u] = W_in[k * PCOLS + j];
            w1[u] = W_in[k * PCOLS + 256 + j];
            w2[u] = has2 ? W_in[k * PCOLS + 512 + j] : 0.f;
        }
        #pragma unroll
        for (int r = 0; r < 2; ++r) {
            #pragma unroll
            for (int q = 0; q < 4; ++q) {
                float4 xv = *(const float4*)&xs[r][kk + q * 4];
                const float xa[4] = {xv.x, xv.y, xv.z, xv.w};
                #pragma unroll
                for (int u = 0; u < 4; ++u) {
                    const int uu = q * 4 + u;
                    acc0[r] = fmaf(xa[u], w0[uu], acc0[r]);
                    acc1[r] = fmaf(xa[u], w1[uu], acc1[r]);
                    acc2[r] = fmaf(xa[u], w2[uu], acc2[r]);
                }
            }
        }
    }

    #pragma unroll
    for (int r = 0; r < 2; ++r) {
        const int row = row0 + r;
        if (has2) {
            draw[r][j] = acc0[r];
            bet[row * NST + 192 + j] = acc1[r];
            gam[row * NST + 192 + j] = acc2[r];
        } else {
            bet[row * NST + (j - 64)] = acc0[r];
            gam[row * NST + (j - 64)] = acc1[r];
        }
    }
    __syncthreads();

    float bd = b_dt[j];
    float accd[2] = {bd, bd};
    #pragma unroll 16
    for (int k = 0; k < DTSZ; ++k) {
        float w = W_dt[k * DIM + j];
        #pragma unroll
        for (int r = 0; r < 2; ++r) accd[r] = fmaf(draw[r][k], w, accd[r]);
    }
    #pragma unroll
    for (int r = 0; r < 2; ++r) {
        const int row = row0 + r;
        float sp = softplusf(accd[r]);
        dtp[row * DIM + j]  = sp;
        dtxp[row * DIM + j] = sp * xs[r][j];
    }
}

// ---------------- scan1p: single-pass scan (R8 skeleton, 54.8us verified) with:
//   (1) barriers halved: reduce every 32 steps (part[32][256], R1-verified scheme)
//   (2) prefetch 3 windows ahead (48 loads in flight; unroll-4 keeps regs static)
//   (3) XCD-locality swizzle: each XCD's L2 serves one batch's beta/gamma
__global__ __launch_bounds__(256) void scan1p(
    const float* __restrict__ x,          // [NROWS, DIM]
    const float* __restrict__ alpha_log,  // [DIM, NST]
    const float* __restrict__ delta,      // [DIM]
    const float* __restrict__ bet,        // [NROWS, NST]
    const float* __restrict__ gam,        // [NROWS, NST]
    const float* __restrict__ dtp,        // [NROWS, DIM]
    const float* __restrict__ dtxp,       // [NROWS, DIM]
    float* __restrict__ out)              // [NROWS, DIM]
{
    __shared__ float part[32][NST];       // 32 KB
    __shared__ float dts[LSEQ], dxs[LSEQ];// 2 KB + 2 KB
    const int n = threadIdx.x;
    // XCD swizzle: xcd = bid&7 (typical round-robin). XCDs 0-3 -> b=0, 4-7 -> b=1.
    const int xcd  = blockIdx.x & 7;
    const int slot = blockIdx.x >> 3;     // 0..63
    const int b = xcd >> 2;
    const int d = slot * 4 + (xcd & 3);   // covers 0..255 per b
    const int rb = b * LSEQ;

    // Stage this d's dt/dtx column for all 512 steps (one-time strided read).
    #pragma unroll
    for (int it = 0; it < 2; ++it) {
        const int l = n + it * 256;
        dts[l] = dtp [(rb + l) * DIM + d];
        dxs[l] = dtxp[(rb + l) * DIM + d];
    }
    const float aln = -__expf(alpha_log[d * NST + n]) * LOG2E;
    const float dv  = delta[d];
    __syncthreads();

    float s = 0.f;
    float be[4][8], ga[4][8];             // 4-slot rotation, 3 windows ahead
    #pragma unroll
    for (int pw = 0; pw < 3; ++pw) {
        #pragma unroll
        for (int t = 0; t < 8; ++t) {
            be[pw][t] = bet[(rb + pw * 8 + t) * NST + n];
            ga[pw][t] = gam[(rb + pw * 8 + t) * NST + n];
        }
    }

    #pragma unroll 4
    for (int w = 0; w < 64; ++w) {
        const int cur = w & 3;
        const int pf  = (w + 3) & 3;
        if (w + 3 < 64) {                 // issue window w+3 while computing w
            #pragma unroll
            for (int t = 0; t < 8; ++t) {
                be[pf][t] = bet[(rb + (w + 3) * 8 + t) * NST + n];
                ga[pf][t] = gam[(rb + (w + 3) * 8 + t) * NST + n];
            }
        }
        // dt/dtx for this window: broadcast b128 LDS reads
        float4 dta = *(const float4*)&dts[w * 8];
        float4 dtb = *(const float4*)&dts[w * 8 + 4];
        float4 dxa = *(const float4*)&dxs[w * 8];
        float4 dxb = *(const float4*)&dxs[w * 8 + 4];
        const float dtw[8] = {dta.x, dta.y, dta.z, dta.w, dtb.x, dtb.y, dtb.z, dtb.w};
        const float dxw[8] = {dxa.x, dxa.y, dxa.z, dxa.w, dxb.x, dxb.y, dxb.z, dxb.w};

        const int prow = (w & 3) * 8;
        #pragma unroll
        for (int t = 0; t < 8; ++t) {
            float a = fexp2(dtw[t] * aln);
            s = fmaf(a, s, dxw[t] * be[cur][t]);
            part[prow + t][n] = s * ga[cur][t];   // 2-way bank alias: free
        }

        if ((w & 3) == 3) {               // every 32 steps: reduce 32 rows x 256
            __syncthreads();
            // R1/R2-verified scheme (measured 0 conflicts):
            // thread = (trow = n>>3, seg = n&7); each sums 32 rotated cols.
            const int trow = n >> 3, seg = n & 7;
            float sum = 0.f;
            #pragma unroll
            for (int k = 0; k < 32; ++k)
                sum += part[trow][seg * 32 + ((k + n) & 31)];
            sum += __shfl_xor(sum, 1);
            sum += __shfl_xor(sum, 2);
            sum += __shfl_xor(sum, 4);
            if (seg == 0) {
                const int r = rb + (w >> 2) * 32 + trow;
                const int oidx = r * DIM + d;
                out[oidx] = sum + x[oidx] * dv;
            }
            __syncthreads();
        }
    }
}

extern "C" void kernel_launch(void* const* d_in, const int* in_sizes, int n_in,
                              void* d_out, int out_size, void* d_ws, size_t ws_size,
                              hipStream_t stream) {
    const float* x         = (const float*)d_in[0];
    const float* W_in      = (const float*)d_in[1];
    const float* W_dt      = (const float*)d_in[2];
    const float* b_dt      = (const float*)d_in[3];
    const float* alpha_log = (const float*)d_in[4];
    const float* delta     = (const float*)d_in[5];
    float* out = (float*)d_out;

    // Workspace: bet/gam/dtp/dtxp = 4 MB total
    float* bet  = (float*)d_ws;
    float* gam  = bet  + NROWS * NST;
    float* dtp  = gam  + NROWS * NST;
    float* dtxp = dtp  + NROWS * DIM;

    proj_kernel<<<NROWS / 2, 256, 0, stream>>>(x, W_in, W_dt, b_dt, bet, gam, dtp, dtxp);
    scan1p<<<BAT * DIM, 256, 0, stream>>>(x, alpha_log, delta, bet, gam, dtp, dtxp, out);
}

// Round 11
// 119.134 us; speedup vs baseline: 2.0632x; 1.0486x over previous
//
#include <hip/hip_runtime.h>
#include <math.h>

// Problem constants
#define DIM   256
#define NST   256
#define LSEQ  512
#define BAT   2
#define DTSZ  64
#define PCOLS 576
#define NROWS 1024

constexpr float LOG2E = 1.4426950408889634f;

__device__ __forceinline__ float fexp2(float v) {
#if __has_builtin(__builtin_amdgcn_exp2f)
    return __builtin_amdgcn_exp2f(v);
#else
    return exp2f(v);
#endif
}

__device__ __forceinline__ float softplusf(float v) {
    return (v > 20.f) ? v : log1pf(__expf(v));
}

// Pack (beta, gamma) as bf16x2 in one dword: beta in low 16, gamma in high 16. RNE.
__device__ __forceinline__ unsigned pack_bg(float be, float ga) {
    unsigned ub = __float_as_uint(be);
    unsigned ug = __float_as_uint(ga);
    ub = (ub + 0x7fffu + ((ub >> 16) & 1u)) >> 16;
    ug = (ug + 0x7fffu + ((ug >> 16) & 1u)) & 0xffff0000u;
    return ub | ug;
}

// ---------------- proj: x@W_in (+ dt GEMM + softplus + dt*x). 512 blocks x 256.
// Identical compute to the R6-verified kernel; beta/gamma now written packed.
__global__ __launch_bounds__(256) void proj_kernel(
    const float* __restrict__ x, const float* __restrict__ W_in,
    const float* __restrict__ W_dt, const float* __restrict__ b_dt,
    unsigned* __restrict__ betgam,     // [NROWS, NST] bf16x2 (beta lo, gamma hi)
    float* __restrict__ dtp, float* __restrict__ dtxp)
{
    __shared__ float xs[2][DIM];
    __shared__ float draw[2][DTSZ];
    const int j = threadIdx.x;
    const int row0 = blockIdx.x * 2;

    #pragma unroll
    for (int r = 0; r < 2; ++r) xs[r][j] = x[(row0 + r) * DIM + j];
    __syncthreads();

    float acc0[2] = {0.f, 0.f}, acc1[2] = {0.f, 0.f}, acc2[2] = {0.f, 0.f};
    const bool has2 = (j < 64);

    for (int kk = 0; kk < DIM; kk += 16) {
        float w0[16], w1[16], w2[16];
        #pragma unroll
        for (int u = 0; u < 16; ++u) {
            const int k = kk + u;
            w0[u] = W_in[k * PCOLS + j];
            w1[u] = W_in[k * PCOLS + 256 + j];
            w2[u] = has2 ? W_in[k * PCOLS + 512 + j] : 0.f;
        }
        #pragma unroll
        for (int r = 0; r < 2; ++r) {
            #pragma unroll
            for (int q = 0; q < 4; ++q) {
                float4 xv = *(const float4*)&xs[r][kk + q * 4];
                const float xa[4] = {xv.x, xv.y, xv.z, xv.w};
                #pragma unroll
                for (int u = 0; u < 4; ++u) {
                    const int uu = q * 4 + u;
                    acc0[r] = fmaf(xa[u], w0[uu], acc0[r]);
                    acc1[r] = fmaf(xa[u], w1[uu], acc1[r]);
                    acc2[r] = fmaf(xa[u], w2[uu], acc2[r]);
                }
            }
        }
    }

    // proj col split: [0,64)=dt_raw, [64,320)=beta, [320,576)=gamma.
    // Thread j owns cols {j, 256+j, 512+j(j<64)}; beta & gamma for the same
    // output index land on the same thread -> packing is free.
    #pragma unroll
    for (int r = 0; r < 2; ++r) {
        const int row = row0 + r;
        if (has2) {
            draw[r][j] = acc0[r];
            betgam[row * NST + 192 + j] = pack_bg(acc1[r], acc2[r]);
        } else {
            betgam[row * NST + (j - 64)] = pack_bg(acc0[r], acc1[r]);
        }
    }
    __syncthreads();

    float bd = b_dt[j];
    float accd[2] = {bd, bd};
    #pragma unroll 16
    for (int k = 0; k < DTSZ; ++k) {
        float w = W_dt[k * DIM + j];
        #pragma unroll
        for (int r = 0; r < 2; ++r) accd[r] = fmaf(draw[r][k], w, accd[r]);
    }
    #pragma unroll
    for (int r = 0; r < 2; ++r) {
        const int row = row0 + r;
        float sp = softplusf(accd[r]);
        dtp[row * DIM + j]  = sp;
        dtxp[row * DIM + j] = sp * xs[r][j];
    }
}

// ---------------- scan1p: single-pass scan (R10 skeleton, 43.3us verified),
// now reading ONE packed bf16x2 dword per step instead of two fp32:
// L2 read traffic 512 -> 256 MB, VMEM issue halved, prefetch regs halved.
__global__ __launch_bounds__(256) void scan1p(
    const float* __restrict__ x,            // [NROWS, DIM]
    const float* __restrict__ alpha_log,    // [DIM, NST]
    const float* __restrict__ delta,        // [DIM]
    const unsigned* __restrict__ betgam,    // [NROWS, NST] packed
    const float* __restrict__ dtp,          // [NROWS, DIM]
    const float* __restrict__ dtxp,         // [NROWS, DIM]
    float* __restrict__ out)                // [NROWS, DIM]
{
    __shared__ float part[32][NST];       // 32 KB
    __shared__ float dts[LSEQ], dxs[LSEQ];// 2 KB + 2 KB
    const int n = threadIdx.x;
    // XCD swizzle (R10-verified): XCDs 0-3 -> b=0, 4-7 -> b=1.
    const int xcd  = blockIdx.x & 7;
    const int slot = blockIdx.x >> 3;     // 0..63
    const int b = xcd >> 2;
    const int d = slot * 4 + (xcd & 3);
    const int rb = b * LSEQ;

    #pragma unroll
    for (int it = 0; it < 2; ++it) {
        const int l = n + it * 256;
        dts[l] = dtp [(rb + l) * DIM + d];
        dxs[l] = dtxp[(rb + l) * DIM + d];
    }
    const float aln = -__expf(alpha_log[d * NST + n]) * LOG2E;
    const float dv  = delta[d];
    __syncthreads();

    float s = 0.f;
    unsigned bg[4][8];                    // 4-slot rotation, 3 windows ahead
    #pragma unroll
    for (int pw = 0; pw < 3; ++pw) {
        #pragma unroll
        for (int t = 0; t < 8; ++t)
            bg[pw][t] = betgam[(rb + pw * 8 + t) * NST + n];
    }

    #pragma unroll 4
    for (int w = 0; w < 64; ++w) {
        const int cur = w & 3;
        const int pf  = (w + 3) & 3;
        if (w + 3 < 64) {                 // issue window w+3 while computing w
            #pragma unroll
            for (int t = 0; t < 8; ++t)
                bg[pf][t] = betgam[(rb + (w + 3) * 8 + t) * NST + n];
        }
        float4 dta = *(const float4*)&dts[w * 8];
        float4 dtb = *(const float4*)&dts[w * 8 + 4];
        float4 dxa = *(const float4*)&dxs[w * 8];
        float4 dxb = *(const float4*)&dxs[w * 8 + 4];
        const float dtw[8] = {dta.x, dta.y, dta.z, dta.w, dtb.x, dtb.y, dtb.z, dtb.w};
        const float dxw[8] = {dxa.x, dxa.y, dxa.z, dxa.w, dxb.x, dxb.y, dxb.z, dxb.w};

        const int prow = (w & 3) * 8;
        #pragma unroll
        for (int t = 0; t < 8; ++t) {
            const unsigned u = bg[cur][t];
            const float be = __uint_as_float(u << 16);
            const float ga = __uint_as_float(u & 0xffff0000u);
            float a = fexp2(dtw[t] * aln);
            s = fmaf(a, s, dxw[t] * be);
            part[prow + t][n] = s * ga;   // 2-way bank alias: free
        }

        if ((w & 3) == 3) {               // every 32 steps: reduce 32 rows x 256
            __syncthreads();
            const int trow = n >> 3, seg = n & 7;
            float sum = 0.f;
            #pragma unroll
            for (int k = 0; k < 32; ++k)
                sum += part[trow][seg * 32 + ((k + n) & 31)];   // measured 0-conflict
            sum += __shfl_xor(sum, 1);
            sum += __shfl_xor(sum, 2);
            sum += __shfl_xor(sum, 4);
            if (seg == 0) {
                const int r = rb + (w >> 2) * 32 + trow;
                const int oidx = r * DIM + d;
                out[oidx] = sum + x[oidx] * dv;
            }
            __syncthreads();
        }
    }
}

extern "C" void kernel_launch(void* const* d_in, const int* in_sizes, int n_in,
                              void* d_out, int out_size, void* d_ws, size_t ws_size,
                              hipStream_t stream) {
    const float* x         = (const float*)d_in[0];
    const float* W_in      = (const float*)d_in[1];
    const float* W_dt      = (const float*)d_in[2];
    const float* b_dt      = (const float*)d_in[3];
    const float* alpha_log = (const float*)d_in[4];
    const float* delta     = (const float*)d_in[5];
    float* out = (float*)d_out;

    // Workspace: betgam 1MB + dtp/dtxp 2MB = 3 MB
    unsigned* betgam = (unsigned*)d_ws;
    float* dtp  = (float*)(betgam + NROWS * NST);
    float* dtxp = dtp + NROWS * DIM;

    proj_kernel<<<NROWS / 2, 256, 0, stream>>>(x, W_in, W_dt, b_dt, betgam, dtp, dtxp);
    scan1p<<<BAT * DIM, 256, 0, stream>>>(x, alpha_log, delta, betgam, dtp, dtxp, out);
}

// Round 12
// 119.054 us; speedup vs baseline: 2.0646x; 1.0007x over previous
//
#include <hip/hip_runtime.h>
#include <math.h>

// Problem constants
#define DIM   256
#define NST   256
#define LSEQ  512
#define BAT   2
#define DTSZ  64
#define PCOLS 576
#define NROWS 1024

constexpr float LOG2E = 1.4426950408889634f;

__device__ __forceinline__ float fexp2(float v) {
#if __has_builtin(__builtin_amdgcn_exp2f)
    return __builtin_amdgcn_exp2f(v);
#else
    return exp2f(v);
#endif
}

__device__ __forceinline__ float softplusf(float v) {
    return (v > 20.f) ? v : log1pf(__expf(v));
}

// Split barrier: wait LDS ops only (lgkmcnt(0)), leave VMEM (vmcnt) in flight
// across s_barrier — the AITER/hipBLASLt technique. gfx9 waitcnt encoding:
// simm16 = vmcnt[3:0] | expcnt<<4 | lgkmcnt<<8 | vmcnt[5:4]<<14.
// vmcnt=63, expcnt=7, lgkmcnt=0 -> 0xC07F.
__device__ __forceinline__ void barrier_lds_only() {
    __builtin_amdgcn_s_waitcnt(0xC07F);
    __builtin_amdgcn_s_barrier();
}

// Pack (beta, gamma) as bf16x2 in one dword: beta in low 16, gamma in high 16. RNE.
__device__ __forceinline__ unsigned pack_bg(float be, float ga) {
    unsigned ub = __float_as_uint(be);
    unsigned ug = __float_as_uint(ga);
    ub = (ub + 0x7fffu + ((ub >> 16) & 1u)) >> 16;
    ug = (ug + 0x7fffu + ((ug >> 16) & 1u)) & 0xffff0000u;
    return ub | ug;
}

// ---------------- proj: x@W_in (+ dt GEMM + softplus + dt*x). 512 blocks x 256.
// (verified since R6; betgam packing verified R11)
__global__ __launch_bounds__(256) void proj_kernel(
    const float* __restrict__ x, const float* __restrict__ W_in,
    const float* __restrict__ W_dt, const float* __restrict__ b_dt,
    unsigned* __restrict__ betgam,     // [NROWS, NST] bf16x2 (beta lo, gamma hi)
    float* __restrict__ dtp, float* __restrict__ dtxp)
{
    __shared__ float xs[2][DIM];
    __shared__ float draw[2][DTSZ];
    const int j = threadIdx.x;
    const int row0 = blockIdx.x * 2;

    #pragma unroll
    for (int r = 0; r < 2; ++r) xs[r][j] = x[(row0 + r) * DIM + j];
    __syncthreads();

    float acc0[2] = {0.f, 0.f}, acc1[2] = {0.f, 0.f}, acc2[2] = {0.f, 0.f};
    const bool has2 = (j < 64);

    for (int kk = 0; kk < DIM; kk += 16) {
        float w0[16], w1[16], w2[16];
        #pragma unroll
        for (int u = 0; u < 16; ++u) {
            const int k = kk + u;
            w0[u] = W_in[k * PCOLS + j];
            w1[u] = W_in[k * PCOLS + 256 + j];
            w2[u] = has2 ? W_in[k * PCOLS + 512 + j] : 0.f;
        }
        #pragma unroll
        for (int r = 0; r < 2; ++r) {
            #pragma unroll
            for (int q = 0; q < 4; ++q) {
                float4 xv = *(const float4*)&xs[r][kk + q * 4];
                const float xa[4] = {xv.x, xv.y, xv.z, xv.w};
                #pragma unroll
                for (int u = 0; u < 4; ++u) {
                    const int uu = q * 4 + u;
                    acc0[r] = fmaf(xa[u], w0[uu], acc0[r]);
                    acc1[r] = fmaf(xa[u], w1[uu], acc1[r]);
                    acc2[r] = fmaf(xa[u], w2[uu], acc2[r]);
                }
            }
        }
    }

    #pragma unroll
    for (int r = 0; r < 2; ++r) {
        const int row = row0 + r;
        if (has2) {
            draw[r][j] = acc0[r];
            betgam[row * NST + 192 + j] = pack_bg(acc1[r], acc2[r]);
        } else {
            betgam[row * NST + (j - 64)] = pack_bg(acc0[r], acc1[r]);
        }
    }
    __syncthreads();

    float bd = b_dt[j];
    float accd[2] = {bd, bd};
    #pragma unroll 16
    for (int k = 0; k < DTSZ; ++k) {
        float w = W_dt[k * DIM + j];
        #pragma unroll
        for (int r = 0; r < 2; ++r) accd[r] = fmaf(draw[r][k], w, accd[r]);
    }
    #pragma unroll
    for (int r = 0; r < 2; ++r) {
        const int row = row0 + r;
        float sp = softplusf(accd[r]);
        dtp[row * DIM + j]  = sp;
        dtxp[row * DIM + j] = sp * xs[r][j];
    }
}

// ---------------- scan1p: single-pass scan (R10/R11 skeleton, verified) with
// in-loop barriers downgraded to LDS-only (vmcnt queue survives all 16 pairs).
__global__ __launch_bounds__(256) void scan1p(
    const float* __restrict__ x,            // [NROWS, DIM]
    const float* __restrict__ alpha_log,    // [DIM, NST]
    const float* __restrict__ delta,        // [DIM]
    const unsigned* __restrict__ betgam,    // [NROWS, NST] packed
    const float* __restrict__ dtp,          // [NROWS, DIM]
    const float* __restrict__ dtxp,         // [NROWS, DIM]
    float* __restrict__ out)                // [NROWS, DIM]
{
    __shared__ float part[32][NST];       // 32 KB
    __shared__ float dts[LSEQ], dxs[LSEQ];// 2 KB + 2 KB
    const int n = threadIdx.x;
    // XCD swizzle (R10-verified): XCDs 0-3 -> b=0, 4-7 -> b=1.
    const int xcd  = blockIdx.x & 7;
    const int slot = blockIdx.x >> 3;     // 0..63
    const int b = xcd >> 2;
    const int d = slot * 4 + (xcd & 3);
    const int rb = b * LSEQ;

    #pragma unroll
    for (int it = 0; it < 2; ++it) {
        const int l = n + it * 256;
        dts[l] = dtp [(rb + l) * DIM + d];
        dxs[l] = dtxp[(rb + l) * DIM + d];
    }
    const float aln = -__expf(alpha_log[d * NST + n]) * LOG2E;
    const float dv  = delta[d];
    __syncthreads();                      // full barrier: global->LDS staging dep

    float s = 0.f;
    unsigned bg[4][8];                    // 4-slot rotation, 3 windows ahead
    #pragma unroll
    for (int pw = 0; pw < 3; ++pw) {
        #pragma unroll
        for (int t = 0; t < 8; ++t)
            bg[pw][t] = betgam[(rb + pw * 8 + t) * NST + n];
    }

    #pragma unroll 4
    for (int w = 0; w < 64; ++w) {
        const int cur = w & 3;
        const int pf  = (w + 3) & 3;
        if (w + 3 < 64) {                 // issue window w+3 while computing w
            #pragma unroll
            for (int t = 0; t < 8; ++t)
                bg[pf][t] = betgam[(rb + (w + 3) * 8 + t) * NST + n];
        }
        float4 dta = *(const float4*)&dts[w * 8];
        float4 dtb = *(const float4*)&dts[w * 8 + 4];
        float4 dxa = *(const float4*)&dxs[w * 8];
        float4 dxb = *(const float4*)&dxs[w * 8 + 4];
        const float dtw[8] = {dta.x, dta.y, dta.z, dta.w, dtb.x, dtb.y, dtb.z, dtb.w};
        const float dxw[8] = {dxa.x, dxa.y, dxa.z, dxa.w, dxb.x, dxb.y, dxb.z, dxb.w};

        const int prow = (w & 3) * 8;
        #pragma unroll
        for (int t = 0; t < 8; ++t) {
            const unsigned u = bg[cur][t];
            const float be = __uint_as_float(u << 16);
            const float ga = __uint_as_float(u & 0xffff0000u);
            float a = fexp2(dtw[t] * aln);
            s = fmaf(a, s, dxw[t] * be);
            part[prow + t][n] = s * ga;   // 2-way bank alias: free
        }

        if ((w & 3) == 3) {               // every 32 steps: reduce 32 rows x 256
            barrier_lds_only();           // LDS-ordering only; vmcnt stays in flight
            const int trow = n >> 3, seg = n & 7;
            float sum = 0.f;
            #pragma unroll
            for (int k = 0; k < 32; ++k)
                sum += part[trow][seg * 32 + ((k + n) & 31)];   // measured 0-conflict
            sum += __shfl_xor(sum, 1);
            sum += __shfl_xor(sum, 2);
            sum += __shfl_xor(sum, 4);
            if (seg == 0) {
                const int r = rb + (w >> 2) * 32 + trow;
                const int oidx = r * DIM + d;
                out[oidx] = sum + x[oidx] * dv;
            }
            barrier_lds_only();           // WAR: reads done before next window writes
        }
    }
}

extern "C" void kernel_launch(void* const* d_in, const int* in_sizes, int n_in,
                              void* d_out, int out_size, void* d_ws, size_t ws_size,
                              hipStream_t stream) {
    const float* x         = (const float*)d_in[0];
    const float* W_in      = (const float*)d_in[1];
    const float* W_dt      = (const float*)d_in[2];
    const float* b_dt      = (const float*)d_in[3];
    const float* alpha_log = (const float*)d_in[4];
    const float* delta     = (const float*)d_in[5];
    float* out = (float*)d_out;

    // Workspace: betgam 1MB + dtp/dtxp 2MB = 3 MB
    unsigned* betgam = (unsigned*)d_ws;
    float* dtp  = (float*)(betgam + NROWS * NST);
    float* dtxp = dtp + NROWS * DIM;

    proj_kernel<<<NROWS / 2, 256, 0, stream>>>(x, W_in, W_dt, b_dt, betgam, dtp, dtxp);
    scan1p<<<BAT * DIM, 256, 0, stream>>>(x, alpha_log, delta, betgam, dtp, dtxp, out);
}

// Round 13
// 118.716 us; speedup vs baseline: 2.0705x; 1.0029x over previous
//
#include <hip/hip_runtime.h>
#include <math.h>

// Problem constants
#define DIM   256
#define NST   256
#define LSEQ  512
#define BAT   2
#define DTSZ  64
#define PCOLS 576
#define NROWS 1024

constexpr float LOG2E = 1.4426950408889634f;

__device__ __forceinline__ float fexp2(float v) {
#if __has_builtin(__builtin_amdgcn_exp2f)
    return __builtin_amdgcn_exp2f(v);
#else
    return exp2f(v);
#endif
}

__device__ __forceinline__ float softplusf(float v) {
    return (v > 20.f) ? v : log1pf(__expf(v));
}

// LDS-only barrier (kept from R12 — harmless, occasionally helps scheduling).
__device__ __forceinline__ void barrier_lds_only() {
    __builtin_amdgcn_s_waitcnt(0xC07F);   // vmcnt=63, expcnt=7, lgkmcnt=0
    __builtin_amdgcn_s_barrier();
}

// Pack (beta, gamma) as bf16x2 in one dword: beta lo16, gamma hi16. RNE.
__device__ __forceinline__ unsigned pack_bg(float be, float ga) {
    unsigned ub = __float_as_uint(be);
    unsigned ug = __float_as_uint(ga);
    ub = (ub + 0x7fffu + ((ub >> 16) & 1u)) >> 16;
    ug = (ug + 0x7fffu + ((ug >> 16) & 1u)) & 0xffff0000u;
    return ub | ug;
}

// ---------------- proj: x@W_in (+ dt GEMM + softplus + dt*x). 512 blocks x 256.
// (verified since R6; betgam packing verified R11)
__global__ __launch_bounds__(256) void proj_kernel(
    const float* __restrict__ x, const float* __restrict__ W_in,
    const float* __restrict__ W_dt, const float* __restrict__ b_dt,
    unsigned* __restrict__ betgam,     // [NROWS, NST] bf16x2
    float* __restrict__ dtp, float* __restrict__ dtxp)
{
    __shared__ float xs[2][DIM];
    __shared__ float draw[2][DTSZ];
    const int j = threadIdx.x;
    const int row0 = blockIdx.x * 2;

    #pragma unroll
    for (int r = 0; r < 2; ++r) xs[r][j] = x[(row0 + r) * DIM + j];
    __syncthreads();

    float acc0[2] = {0.f, 0.f}, acc1[2] = {0.f, 0.f}, acc2[2] = {0.f, 0.f};
    const bool has2 = (j < 64);

    for (int kk = 0; kk < DIM; kk += 16) {
        float w0[16], w1[16], w2[16];
        #pragma unroll
        for (int u = 0; u < 16; ++u) {
            const int k = kk + u;
            w0[u] = W_in[k * PCOLS + j];
            w1[u] = W_in[k * PCOLS + 256 + j];
            w2[u] = has2 ? W_in[k * PCOLS + 512 + j] : 0.f;
        }
        #pragma unroll
        for (int r = 0; r < 2; ++r) {
            #pragma unroll
            for (int q = 0; q < 4; ++q) {
                float4 xv = *(const float4*)&xs[r][kk + q * 4];
                const float xa[4] = {xv.x, xv.y, xv.z, xv.w};
                #pragma unroll
                for (int u = 0; u < 4; ++u) {
                    const int uu = q * 4 + u;
                    acc0[r] = fmaf(xa[u], w0[uu], acc0[r]);
                    acc1[r] = fmaf(xa[u], w1[uu], acc1[r]);
                    acc2[r] = fmaf(xa[u], w2[uu], acc2[r]);
                }
            }
        }
    }

    #pragma unroll
    for (int r = 0; r < 2; ++r) {
        const int row = row0 + r;
        if (has2) {
            draw[r][j] = acc0[r];
            betgam[row * NST + 192 + j] = pack_bg(acc1[r], acc2[r]);
        } else {
            betgam[row * NST + (j - 64)] = pack_bg(acc0[r], acc1[r]);
        }
    }
    __syncthreads();

    float bd = b_dt[j];
    float accd[2] = {bd, bd};
    #pragma unroll 16
    for (int k = 0; k < DTSZ; ++k) {
        float w = W_dt[k * DIM + j];
        #pragma unroll
        for (int r = 0; r < 2; ++r) accd[r] = fmaf(draw[r][k], w, accd[r]);
    }
    #pragma unroll
    for (int r = 0; r < 2; ++r) {
        const int row = row0 + r;
        float sp = softplusf(accd[r]);
        dtp[row * DIM + j]  = sp;
        dtxp[row * DIM + j] = sp * xs[r][j];
    }
}

// ---------------- scan1p: single-pass scan (R10/R11 skeleton) with prefetch
// distance stretched to 6 windows (~900-1000 cyc of issue) to cover HBM
// compulsory-miss latency; 8-slot rotation, unroll-8 keeps indices static.
__global__ __launch_bounds__(256) void scan1p(
    const float* __restrict__ x,            // [NROWS, DIM]
    const float* __restrict__ alpha_log,    // [DIM, NST]
    const float* __restrict__ delta,        // [DIM]
    const unsigned* __restrict__ betgam,    // [NROWS, NST] packed
    const float* __restrict__ dtp,          // [NROWS, DIM]
    const float* __restrict__ dtxp,         // [NROWS, DIM]
    float* __restrict__ out)                // [NROWS, DIM]
{
    __shared__ float part[32][NST];         // 32 KB
    __shared__ float dts[LSEQ], dxs[LSEQ], xcol[LSEQ];   // 3 x 2 KB
    const int n = threadIdx.x;
    // XCD swizzle (R10-verified): XCDs 0-3 -> b=0, 4-7 -> b=1.
    const int xcd  = blockIdx.x & 7;
    const int slot = blockIdx.x >> 3;       // 0..63
    const int b = xcd >> 2;
    const int d = slot * 4 + (xcd & 3);
    const int rb = b * LSEQ;

    #pragma unroll
    for (int it = 0; it < 2; ++it) {
        const int l = n + it * 256;
        dts[l]  = dtp [(rb + l) * DIM + d];
        dxs[l]  = dtxp[(rb + l) * DIM + d];
        xcol[l] = x   [(rb + l) * DIM + d];
    }
    const float aln = -__expf(alpha_log[d * NST + n]) * LOG2E;
    const float dv  = delta[d];
    __syncthreads();                        // staging dep (global->LDS)

    float s = 0.f;
    unsigned bg[8][8];                      // 8-slot rotation, 6 windows ahead
    #pragma unroll
    for (int pw = 0; pw < 6; ++pw) {
        #pragma unroll
        for (int t = 0; t < 8; ++t)
            bg[pw][t] = betgam[(rb + pw * 8 + t) * NST + n];
    }

    #pragma unroll 8
    for (int w = 0; w < 64; ++w) {
        const int cur = w & 7;
        const int pf  = (w + 6) & 7;
        if (w + 6 < 64) {                   // issue window w+6 while computing w
            #pragma unroll
            for (int t = 0; t < 8; ++t)
                bg[pf][t] = betgam[(rb + (w + 6) * 8 + t) * NST + n];
        }
        float4 dta = *(const float4*)&dts[w * 8];
        float4 dtb = *(const float4*)&dts[w * 8 + 4];
        float4 dxa = *(const float4*)&dxs[w * 8];
        float4 dxb = *(const float4*)&dxs[w * 8 + 4];
        const float dtw[8] = {dta.x, dta.y, dta.z, dta.w, dtb.x, dtb.y, dtb.z, dtb.w};
        const float dxw[8] = {dxa.x, dxa.y, dxa.z, dxa.w, dxb.x, dxb.y, dxb.z, dxb.w};

        const int prow = (w & 3) * 8;
        #pragma unroll
        for (int t = 0; t < 8; ++t) {
            const unsigned u = bg[cur][t];
            const float be = __uint_as_float(u << 16);
            const float ga = __uint_as_float(u & 0xffff0000u);
            float a = fexp2(dtw[t] * aln);
            s = fmaf(a, s, dxw[t] * be);
            part[prow + t][n] = s * ga;     // 2-way bank alias: free
        }

        if ((w & 3) == 3) {                 // every 32 steps: reduce 32 rows x 256
            barrier_lds_only();
            const int trow = n >> 3, seg = n & 7;
            float sum = 0.f;
            #pragma unroll
            for (int k = 0; k < 32; ++k)
                sum += part[trow][seg * 32 + ((k + n) & 31)];   // measured 0-conflict
            sum += __shfl_xor(sum, 1);
            sum += __shfl_xor(sum, 2);
            sum += __shfl_xor(sum, 4);
            if (seg == 0) {
                const int l = (w >> 2) * 32 + trow;
                out[(rb + l) * DIM + d] = sum + xcol[l] * dv;
            }
            barrier_lds_only();             // WAR before next window's writes
        }
    }
}

extern "C" void kernel_launch(void* const* d_in, const int* in_sizes, int n_in,
                              void* d_out, int out_size, void* d_ws, size_t ws_size,
                              hipStream_t stream) {
    const float* x         = (const float*)d_in[0];
    const float* W_in      = (const float*)d_in[1];
    const float* W_dt      = (const float*)d_in[2];
    const float* b_dt      = (const float*)d_in[3];
    const float* alpha_log = (const float*)d_in[4];
    const float* delta     = (const float*)d_in[5];
    float* out = (float*)d_out;

    // Workspace: betgam 1MB + dtp/dtxp 2MB = 3 MB
    unsigned* betgam = (unsigned*)d_ws;
    float* dtp  = (float*)(betgam + NROWS * NST);
    float* dtxp = dtp + NROWS * DIM;

    proj_kernel<<<NROWS / 2, 256, 0, stream>>>(x, W_in, W_dt, b_dt, betgam, dtp, dtxp);
    scan1p<<<BAT * DIM, 256, 0, stream>>>(x, alpha_log, delta, betgam, dtp, dtxp, out);
}